// Round 15
// baseline (405.386 us; speedup 1.0000x reference)
//
#include <hip/hip_runtime.h>

typedef unsigned short u16;
typedef __attribute__((ext_vector_type(4))) float float4v;
typedef __attribute__((ext_vector_type(4))) unsigned short ushort4v;
typedef __attribute__((ext_vector_type(8))) unsigned short ushort8v;
typedef __attribute__((ext_vector_type(8))) short bf16x8;
typedef __attribute__((ext_vector_type(4))) float f32x4;

#define DEV static __device__ __forceinline__

#define VT_STRIDE 4144   // 16 left pad + 4096 + 32 right pad

DEV u16 f2bf(float f) {
  unsigned u = __float_as_uint(f);
  u += 0x7fffu + ((u >> 16) & 1u);
  return (u16)(u >> 16);
}
DEV float bf2f(u16 h) { return __uint_as_float(((unsigned)h) << 16); }

DEV void gload16(const void* g, void* l) {
  __builtin_amdgcn_global_load_lds((const __attribute__((address_space(1))) unsigned int*)g,
                                   (__attribute__((address_space(3))) unsigned int*)l, 16, 0, 0);
}

// ---------- merged prep: x cvt+landmark partials | W cvt | vt pad borders ----------
__global__ __launch_bounds__(256) void k_prep(
    const float* __restrict__ x, u16* __restrict__ xb, float* __restrict__ xlp,
    float* __restrict__ scl,
    const float* __restrict__ Wq, const float* __restrict__ Wk,
    const float* __restrict__ Wv, const float* __restrict__ Wo,
    u16* __restrict__ wall, u16* __restrict__ vt) {
  int blk = blockIdx.x;
  if (blk < 512) {
    int bm = blk >> 1, half = blk & 1;
    if (blk == 0 && threadIdx.x == 0) { scl[0] = 0.f; scl[1] = 0.f; }
    int d0 = threadIdx.x * 4;
    const float* base = x + (size_t)bm * 65536 + (size_t)half * 32768 + d0;
    u16* ob = xb + (size_t)bm * 65536 + (size_t)half * 32768 + d0;
    float4v s0 = {0.f, 0.f, 0.f, 0.f}, s1 = {0.f, 0.f, 0.f, 0.f};
#pragma unroll 8
    for (int n = 0; n < 32; n += 2) {
      float4v v0 = *(const float4v*)(base + n * 1024);
      float4v v1 = *(const float4v*)(base + (n + 1) * 1024);
      s0 += v0;
      s1 += v1;
      ushort4v o0, o1;
#pragma unroll
      for (int e = 0; e < 4; e++) { o0[e] = f2bf(v0[e]); o1[e] = f2bf(v1[e]); }
      *(ushort4v*)(ob + n * 1024) = o0;
      *(ushort4v*)(ob + (n + 1) * 1024) = o1;
    }
    float4v m = s0 + s1;
    *(float4v*)(xlp + ((size_t)half * 256 + bm) * 1024 + d0) = m;
  } else if (blk < 4608) {
    int gtid = (blk - 512) * 256 + threadIdx.x;
    int which = gtid >> 18;
    int off = (gtid & 262143) * 4;
    const float* s = which == 0 ? Wq : (which == 1 ? Wk : (which == 2 ? Wv : Wo));
    float4v v = *(const float4v*)(s + off);
    ushort4v o;
    o[0] = f2bf(v[0]); o[1] = f2bf(v[1]); o[2] = f2bf(v[2]); o[3] = f2bf(v[3]);
    *(ushort4v*)(wall + (size_t)which * 1048576 + off) = o;
  } else {
    int bh = blk - 4608, t = threadIdx.x;
    ushort8v zz = {0,0,0,0,0,0,0,0};
    if (t < 64) {
      u16* z = vt + ((size_t)bh * 64 + t) * VT_STRIDE;
      *(ushort8v*)z = zz; *(ushort8v*)(z + 8) = zz;
    } else if (t < 128) {
      u16* z = vt + ((size_t)bh * 64 + (t - 64)) * VT_STRIDE + 4112;
      *(ushort8v*)z = zz; *(ushort8v*)(z + 8) = zz;
      *(ushort8v*)(z + 16) = zz; *(ushort8v*)(z + 24) = zz;
    }
  }
}

// ---------- 256x256-tile bf16 GEMM, 16 waves (4/SIMD), 8-phase, 16x16x32 MFMA ----------
// C[row,col] = sum_k A[row,k]*Bt[col,k], K=1024, BK=64, 16 waves (4M x 4N), per-wave 64x64.
// B fragments held LIVE across each tile (bfr[4][2], read ph0/ph1, NEVER re-read after the
// buffer's prefetch is issued — the R14 re-read raced with the in-flight global_load_lds).
// vmcnt(2) at ph0/ph4 (6 outstanding at entry, wait oldest 4), vmcnt(0) final iteration.
// MODE 0: Bt=[Wq;Wk;Wv]; q,k scattered bf16 (q/8); v TRANSPOSED into padded vt.
// MODE 1: Bt=Wo; fp32 linear [row*1024+col].
template<int MODE>
__global__ __launch_bounds__(1024, 1) void k_gemm256(
    const u16* __restrict__ A, const u16* __restrict__ Bt,
    u16* __restrict__ oq, u16* __restrict__ ok, u16* __restrict__ ovt,
    float* __restrict__ outf, int NBN) {
  __shared__ u16 smem[65536];          // A: [0,32768) u16, B: [32768,65536)
  const int K = 1024;
  const int tid = threadIdx.x;
  const int w = tid >> 6, l = tid & 63;   // w in 0..15
  const int lr = l & 15;               // fragment row within 16
  const int lg = l >> 4;               // k-subgroup 0..3

  // XCD-bijective block swizzle (nwg % 8 == 0 for all our launches)
  const int nwg = gridDim.x;
  const int q8 = nwg >> 3;
  const int wg = ((int)blockIdx.x & 7) * q8 + ((int)blockIdx.x >> 3);
  const int bn = wg % NBN, bm = wg / NBN;
  const int wm = w >> 2, wn = w & 3;   // wave tile: rows wm*64, cols wn*64

  // staging source swizzle (inverse of read-side; row&7 = l>>3)
  const int srow = l >> 3;
  const int scol = ((l & 7) ^ srow) * 8;

  // stage one A/B row-half (128 rows x 64 K-cols = 16 KB = 1 gload across 16 waves)
  auto stageA = [&](int d, int h, int t) {
    const u16* g = A + (size_t)(bm * 256 + h * 128 + w * 8 + srow) * K + t * 64 + scol;
    gload16(g, smem + (d * 2 + h) * 8192 + w * 512);
  };
  auto stageB = [&](int d, int h, int t) {
    const u16* g = Bt + (size_t)(bn * 256 + h * 128 + w * 8 + srow) * K + t * 64 + scol;
    gload16(g, smem + 32768 + (d * 2 + h) * 8192 + w * 512);
  };
  // fragment reads (this wave's panels; row&7 = lr&7 -> 0-conflict slot)
  auto rdA = [&](int d, int mf, int ks) -> bf16x8 {
    return *(const bf16x8*)(smem + d * 16384 + (wm >> 1) * 8192
                            + ((wm & 1) * 64 + mf * 16 + lr) * 64 + (((ks * 4 + lg) ^ (lr & 7)) << 3));
  };
  auto rdB = [&](int d, int nf, int ks) -> bf16x8 {
    return *(const bf16x8*)(smem + 32768 + d * 16384 + (wn >> 1) * 8192
                            + ((wn & 1) * 64 + nf * 16 + lr) * 64 + (((ks * 4 + lg) ^ (lr & 7)) << 3));
  };

  f32x4 acc[4][4];
  f32x4 zero = {0.f, 0.f, 0.f, 0.f};
#pragma unroll
  for (int i = 0; i < 4; i++)
#pragma unroll
    for (int j = 0; j < 4; j++) acc[i][j] = zero;

#define PH_MFMA(MBASE, NBASE, BOFF)                                                  \
    asm volatile("s_waitcnt lgkmcnt(0)" ::: "memory");                               \
    __builtin_amdgcn_sched_barrier(0);                                               \
    __builtin_amdgcn_s_setprio(1);                                                   \
    _Pragma("unroll")                                                                \
    for (int ks = 0; ks < 2; ks++)                                                   \
      _Pragma("unroll")                                                              \
      for (int mi = 0; mi < 2; mi++)                                                 \
        _Pragma("unroll")                                                            \
        for (int nj = 0; nj < 2; nj++)                                               \
          acc[(MBASE) + mi][(NBASE) + nj] = __builtin_amdgcn_mfma_f32_16x16x32_bf16( \
              af[mi][ks], bfr[(BOFF) + nj][ks], acc[(MBASE) + mi][(NBASE) + nj], 0, 0, 0); \
    __builtin_amdgcn_s_setprio(0);                                                   \
    __builtin_amdgcn_s_barrier();

  // prologue: tile0 (B,A) + tile1 (B) -> 6 gloads outstanding
  stageB(0, 0, 0); stageB(0, 1, 0);
  stageA(0, 0, 0); stageA(0, 1, 0);
  stageB(1, 0, 1); stageB(1, 1, 1);

  bf16x8 af[2][2], bfr[4][2];
  for (int u = 0; u < 8; u++) {
    const int t1 = 2 * u + 1;
    // ---- ph0: tile t0, mf01 x nf01 ----
    asm volatile("s_waitcnt vmcnt(2)" ::: "memory");   // t0's B+A landed; B(t1) flying
    __builtin_amdgcn_s_barrier();
#pragma unroll
    for (int ks = 0; ks < 2; ks++) {
#pragma unroll
      for (int mi = 0; mi < 2; mi++) af[mi][ks] = rdA(0, mi, ks);
#pragma unroll
      for (int nj = 0; nj < 2; nj++) bfr[nj][ks] = rdB(0, nj, ks);
    }
    stageA(1, 0, t1);
    PH_MFMA(0, 0, 0)
    // ---- ph1: t0, mf01 x nf23 ----
#pragma unroll
    for (int ks = 0; ks < 2; ks++)
#pragma unroll
      for (int nj = 0; nj < 2; nj++) bfr[2 + nj][ks] = rdB(0, 2 + nj, ks);
    stageA(1, 1, t1);
    PH_MFMA(0, 2, 2)
    // ---- ph2: t0, mf23 x nf23 (B(0) fully consumed into regs; safe to overwrite) ----
#pragma unroll
    for (int ks = 0; ks < 2; ks++)
#pragma unroll
      for (int mi = 0; mi < 2; mi++) af[mi][ks] = rdA(0, 2 + mi, ks);
    if (u < 7) stageB(0, 0, 2 * u + 2);
    PH_MFMA(2, 2, 2)
    // ---- ph3: t0, mf23 x nf01 (no LDS reads; operands live) ----
    if (u < 7) stageB(0, 1, 2 * u + 2);
    PH_MFMA(2, 0, 0)
    // ---- ph4: tile t1, mf01 x nf01 ----
    if (u < 7) asm volatile("s_waitcnt vmcnt(2)" ::: "memory");  // B(t1)+A(t1) landed
    else       asm volatile("s_waitcnt vmcnt(0)" ::: "memory");  // no younger loads exist
    __builtin_amdgcn_s_barrier();
#pragma unroll
    for (int ks = 0; ks < 2; ks++) {
#pragma unroll
      for (int mi = 0; mi < 2; mi++) af[mi][ks] = rdA(1, mi, ks);
#pragma unroll
      for (int nj = 0; nj < 2; nj++) bfr[nj][ks] = rdB(1, nj, ks);
    }
    if (u < 7) stageA(0, 0, 2 * u + 2);
    PH_MFMA(0, 0, 0)
    // ---- ph5: t1, mf01 x nf23 ----
#pragma unroll
    for (int ks = 0; ks < 2; ks++)
#pragma unroll
      for (int nj = 0; nj < 2; nj++) bfr[2 + nj][ks] = rdB(1, 2 + nj, ks);
    if (u < 7) stageA(0, 1, 2 * u + 2);
    PH_MFMA(0, 2, 2)
    // ---- ph6: t1, mf23 x nf23 ----
#pragma unroll
    for (int ks = 0; ks < 2; ks++)
#pragma unroll
      for (int mi = 0; mi < 2; mi++) af[mi][ks] = rdA(1, 2 + mi, ks);
    if (u < 7) stageB(1, 0, 2 * u + 3);
    PH_MFMA(2, 2, 2)
    // ---- ph7: t1, mf23 x nf01 (no LDS reads) ----
    if (u < 7) stageB(1, 1, 2 * u + 3);
    PH_MFMA(2, 0, 0)
  }
#undef PH_MFMA

  // epilogue: 16x16 C/D layout: col = lr, row = lg*4 + r
#pragma unroll
  for (int mf = 0; mf < 4; mf++)
#pragma unroll
    for (int nf = 0; nf < 4; nf++) {
      int col  = bn * 256 + wn * 64 + nf * 16 + lr;
      int row0 = bm * 256 + wm * 64 + mf * 16 + lg * 4;
      if (MODE == 1) {
#pragma unroll
        for (int r = 0; r < 4; r++)
          outf[(size_t)(row0 + r) * 1024 + col] = acc[mf][nf][r];
      } else {
        int which = col >> 10;
        int c2 = col & 1023;
        int h = c2 >> 6, hd = c2 & 63;
        if (which == 2) {
          int b = row0 >> 12, nn = row0 & 4095;
          ushort4v pk;
#pragma unroll
          for (int r = 0; r < 4; r++) pk[r] = f2bf(acc[mf][nf][r]);
          *(ushort4v*)(ovt + ((size_t)(b * 16 + h) * 64 + hd) * VT_STRIDE + 16 + nn) = pk;
        } else {
          u16* o = which == 0 ? oq : ok;
          float sc = which == 0 ? 0.125f : 1.f;   // q /= tau = 8
#pragma unroll
          for (int r = 0; r < 4; r++) {
            int row = row0 + r;
            int b = row >> 12, n = row & 4095;
            o[(((size_t)(b * 16 + h)) * 4096 + n) * 64 + hd] = f2bf(acc[mf][nf][r] * sc);
          }
        }
      }
    }
}

// ---------- fp32 landmark projections: ql/kl = mean(x) @ W^T (tiled LDS fp32 GEMM) ----------
__global__ __launch_bounds__(256) void k_landproj(
    const float* __restrict__ xlp,
    const float* __restrict__ Wq, const float* __restrict__ Wk,
    float* __restrict__ ql, float* __restrict__ kl,
    u16* __restrict__ qlb, u16* __restrict__ klb) {
  __shared__ float As[64][68];
  __shared__ float Bs[32][68];
  const int rb = blockIdx.x * 64;
  const int jb = blockIdx.y * 32;
  const int wz = blockIdx.z;
  const float* __restrict__ W = wz ? Wk : Wq;
  const int tid = threadIdx.x;
  const int ty = tid >> 4, tx = tid & 15;
  const int lrow = tid >> 4;
  const int lcol = (tid & 15) * 4;
  float acc[4][2] = {{0.f,0.f},{0.f,0.f},{0.f,0.f},{0.f,0.f}};

  for (int kt = 0; kt < 1024; kt += 64) {
#pragma unroll
    for (int i = 0; i < 4; i++) {
      size_t rbase = (size_t)(rb + lrow + i * 16) * 1024 + kt + lcol;
      float4v v0 = *(const float4v*)(xlp + rbase);
      float4v v1 = *(const float4v*)(xlp + 262144 + rbase);
      float4v v = (v0 + v1) * 0.015625f;   // mean over 64 rows
      *(float4v*)&As[lrow + i * 16][lcol] = v;
    }
#pragma unroll
    for (int i = 0; i < 2; i++) {
      float4v v = *(const float4v*)(W + (size_t)(jb + lrow + i * 16) * 1024 + kt + lcol);
      *(float4v*)&Bs[lrow + i * 16][lcol] = v;
    }
    __syncthreads();
#pragma unroll
    for (int k = 0; k < 64; k += 4) {
      float4v a0 = *(const float4v*)&As[ty * 4 + 0][k];
      float4v a1 = *(const float4v*)&As[ty * 4 + 1][k];
      float4v a2 = *(const float4v*)&As[ty * 4 + 2][k];
      float4v a3 = *(const float4v*)&As[ty * 4 + 3][k];
      float4v b0 = *(const float4v*)&Bs[tx * 2 + 0][k];
      float4v b1 = *(const float4v*)&Bs[tx * 2 + 1][k];
#pragma unroll
      for (int e = 0; e < 4; e++) {
        acc[0][0] += a0[e] * b0[e]; acc[0][1] += a0[e] * b1[e];
        acc[1][0] += a1[e] * b0[e]; acc[1][1] += a1[e] * b1[e];
        acc[2][0] += a2[e] * b0[e]; acc[2][1] += a2[e] * b1[e];
        acc[3][0] += a3[e] * b0[e]; acc[3][1] += a3[e] * b1[e];
      }
    }
    __syncthreads();
  }

  const float s = wz ? 1.f : 0.125f;   // q /= tau = 8
#pragma unroll
  for (int i = 0; i < 4; i++) {
    int row = rb + ty * 4 + i;          // b*64+m
    int b = row >> 6, m = row & 63;
#pragma unroll
    for (int j = 0; j < 2; j++) {
      int col = jb + tx * 2 + j;        // h*64+hd
      int h = col >> 6, hd = col & 63;
      size_t idx = (((size_t)(b * 16 + h)) * 64 + m) * 64 + hd;
      float v = acc[i][j] * s;
      if (wz) { kl[idx] = v; klb[idx] = f2bf(v); }
      else    { ql[idx] = v; qlb[idx] = f2bf(v); }
    }
  }
}

// ---------- merged: a3@v partials (ch 0..15) | a2 softmax + scalars (ch 16) ----------
__global__ __launch_bounds__(256) void k_a3a2(
    const u16* __restrict__ qlb, const u16* __restrict__ kb, const u16* __restrict__ vt,
    float* __restrict__ Zp, float* __restrict__ dp,
    const float* __restrict__ ql, const float* __restrict__ kl,
    float* __restrict__ a2g, float* __restrict__ scalars) {
  __shared__ float smf[3 * 64 * 68];
  int bh = blockIdx.x, ch = blockIdx.y;
  int tid = threadIdx.x;

  if (ch == 16) {
    float* qs = smf;
    float* ksm = smf + 64 * 68;
    float* ss = smf + 2 * 64 * 68;
    for (int e = tid; e < 4096; e += 256) {
      int r = e >> 6, c = e & 63;
      qs[r * 68 + c]  = ql[(size_t)bh * 4096 + e];
      ksm[r * 68 + c] = kl[(size_t)bh * 4096 + e];
    }
    __syncthreads();
    int ty = tid >> 4, tx = tid & 15;
    float acc[4][4];
#pragma unroll
    for (int i = 0; i < 4; i++)
#pragma unroll
      for (int j = 0; j < 4; j++) acc[i][j] = 0.f;
    for (int d = 0; d < 64; d++) {
      float a0 = qs[(ty*4+0)*68+d], a1 = qs[(ty*4+1)*68+d];
      float a2v = qs[(ty*4+2)*68+d], a3v = qs[(ty*4+3)*68+d];
      float b0 = ksm[(tx*4+0)*68+d], b1 = ksm[(tx*4+1)*68+d];
      float b2 = ksm[(tx*4+2)*68+d], b3 = ksm[(tx*4+3)*68+d];
      acc[0][0]+=a0*b0; acc[0][1]+=a0*b1; acc[0][2]+=a0*b2; acc[0][3]+=a0*b3;
      acc[1][0]+=a1*b0; acc[1][1]+=a1*b1; acc[1][2]+=a1*b2; acc[1][3]+=a1*b3;
      acc[2][0]+=a2v*b0; acc[2][1]+=a2v*b1; acc[2][2]+=a2v*b2; acc[2][3]+=a2v*b3;
      acc[3][0]+=a3v*b0; acc[3][1]+=a3v*b1; acc[3][2]+=a3v*b2; acc[3][3]+=a3v*b3;
    }
#pragma unroll
    for (int i = 0; i < 4; i++)
#pragma unroll
      for (int j = 0; j < 4; j++)
        ss[(ty*4+i)*68 + tx*4 + j] = acc[i][j];
    __syncthreads();
    if (tid < 64) {
      float sum = 0.f;
      for (int j = 0; j < 64; j++) {
        float e = __expf(ss[tid * 68 + j]);
        ss[tid * 68 + j] = e; sum += e;
      }
      float inv = 1.f / sum;
      for (int j = 0; j < 64; j++) {
        float p = ss[tid * 68 + j] * inv;
        ss[tid * 68 + j] = p;
        a2g[(size_t)bh * 4096 + tid * 64 + j] = p;
      }
    }
    __syncthreads();
    if (tid < 64) {
      float cs = 0.f, rs = 0.f;
      for (int r = 0; r < 64; r++) cs += ss[r * 68 + tid];
      for (int j = 0; j < 64; j++) rs += ss[tid * 68 + j];
      for (int msk = 1; msk < 64; msk <<= 1) {
        cs = fmaxf(cs, __shfl_xor(cs, msk));
        rs = fmaxf(rs, __shfl_xor(rs, msk));
      }
      if (tid == 0) {
        atomicMax((unsigned int*)&scalars[0], __float_as_uint(rs));
        atomicMax((unsigned int*)&scalars[1], __float_as_uint(cs));
      }
    }
    return;
  }

  u16* Ps = (u16*)smf;
  float* denom_s = smf + 8192;
  int n0 = ch * 256;
  int w = tid >> 6, l = tid & 63;
  int lr = l & 15, lk = (l >> 4) * 8;
  if (tid < 64) denom_s[tid] = 0.f;
  __syncthreads();
  f32x4 zero = {0.f,0.f,0.f,0.f};
  f32x4 sa[4][4];
#pragma unroll
  for (int i = 0; i < 4; i++)
#pragma unroll
    for (int j = 0; j < 4; j++) sa[i][j] = zero;
  const u16* qbase = qlb + (size_t)bh * 4096;
  const u16* kbase = kb + ((size_t)bh * 4096 + n0 + w * 64) * 64;
#pragma unroll
  for (int ks = 0; ks < 2; ks++) {
    bf16x8 af[4], bfr[4];
#pragma unroll
    for (int i = 0; i < 4; i++) {
      af[i]  = *(const bf16x8*)(qbase + (size_t)(i * 16 + lr) * 64 + ks * 32 + lk);
      bfr[i] = *(const bf16x8*)(kbase + (size_t)(i * 16 + lr) * 64 + ks * 32 + lk);
    }
#pragma unroll
    for (int i = 0; i < 4; i++)
#pragma unroll
      for (int j = 0; j < 4; j++)
        sa[i][j] = __builtin_amdgcn_mfma_f32_16x16x32_bf16(af[i], bfr[j], sa[i][j], 0, 0, 0);
  }
#pragma unroll
  for (int i = 0; i < 4; i++) {
#pragma unroll
    for (int r = 0; r < 4; r++) {
      int m = i * 16 + (l >> 4) * 4 + r;
      float rsum = 0.f;
#pragma unroll
      for (int j = 0; j < 4; j++) {
        float p = __expf(sa[i][j][r]);
        rsum += p;
        int n = w * 64 + j * 16 + lr;
        Ps[m * 256 + ((n >> 3) ^ (m & 7)) * 8 + (n & 7)] = f2bf(p);
      }
      rsum += __shfl_xor(rsum, 1);
      rsum += __shfl_xor(rsum, 2);
      rsum += __shfl_xor(rsum, 4);
      rsum += __shfl_xor(rsum, 8);
      if (lr == 0) atomicAdd(&denom_s[m], rsum);
    }
  }
  __syncthreads();
  if (tid < 64) dp[((size_t)ch * 64 + bh) * 64 + tid] = denom_s[tid];
  f32x4 oa[4];
#pragma unroll
  for (int i = 0; i < 4; i++) oa[i] = zero;
  const u16* vtb = vt + ((size_t)bh * 64 + w * 16 + lr) * VT_STRIDE + 16 + n0;
#pragma unroll
  for (int ks = 0; ks < 8; ks++) {
    bf16x8 bv = *(const bf16x8*)(vtb + ks * 32 + lk);
#pragma unroll
    for (int i = 0; i < 4; i++) {
      int row = i * 16 + lr;
      int kk = ks * 32 + lk;
      bf16x8 af = *(const bf16x8*)&Ps[row * 256 + ((kk >> 3) ^ (row & 7)) * 8];
      oa[i] = __builtin_amdgcn_mfma_f32_16x16x32_bf16(af, bv, oa[i], 0, 0, 0);
    }
  }
#pragma unroll
  for (int i = 0; i < 4; i++)
#pragma unroll
    for (int r = 0; r < 4; r++) {
      int m = i * 16 + (l >> 4) * 4 + r;
      int d = w * 16 + lr;
      Zp[(((size_t)ch * 64 + bh) * 64 + m) * 64 + d] = oa[i][r];
    }
}

// ---------- fp32 64x64 matmul in LDS (stride 68), float4 both operands ----------
template<int NEGB>
DEV void mm64x(float* __restrict__ D, const float* A, const float* B, int tid,
               float cB, float scale) {
  int ty = tid >> 4, tx = tid & 15;
  float acc[4][4];
#pragma unroll
  for (int i = 0; i < 4; i++)
#pragma unroll
    for (int j = 0; j < 4; j++) acc[i][j] = 0.f;
  const float* a0p = A + (ty * 4 + 0) * 68;
  const float* a1p = A + (ty * 4 + 1) * 68;
  const float* a2p = A + (ty * 4 + 2) * 68;
  const float* a3p = A + (ty * 4 + 3) * 68;
#pragma unroll 4
  for (int k = 0; k < 64; k += 4) {
    float4v av0 = *(const float4v*)(a0p + k);
    float4v av1 = *(const float4v*)(a1p + k);
    float4v av2 = *(const float4v*)(a2p + k);
    float4v av3 = *(const float4v*)(a3p + k);
    float4v b0 = *(const float4v*)&B[(k + 0) * 68 + tx * 4];
    float4v b1 = *(const float4v*)&B[(k + 1) * 68 + tx * 4];
    float4v b2 = *(const float4v*)&B[(k + 2) * 68 + tx * 4];
    float4v b3 = *(const float4v*)&B[(k + 3) * 68 + tx * 4];
    if (NEGB) {
      b0 = -b0; b1 = -b1; b2 = -b2; b3 = -b3;
      if (k == tx * 4) { b0[0] += cB; b1[1] += cB; b2[2] += cB; b3[3] += cB; }
    }
#pragma unroll
    for (int j = 0; j < 4; j++) {
      acc[0][j] = fmaf(av0[3], b3[j], fmaf(av0[2], b2[j], fmaf(av0[1], b1[j], fmaf(av0[0], b0[j], acc[0][j]))));
      acc[1][j] = fmaf(av1[3], b3[j], fmaf(av1[2], b2[j], fmaf(av1[1], b1[j], fmaf(av1[0], b0[j], acc[1][j]))));
      acc[2][j] = fmaf(av2[3], b3[j], fmaf(av2[2], b2[j], fmaf(av2[1], b1[j], fmaf(av2[0], b0[j], acc[2][j]))));
      acc[3][j] = fmaf(av3[3], b3[j], fmaf(av3[2], b2[j], fmaf(av3[1], b1[j], fmaf(av3[0], b0[j], acc[3][j]))));
    }
  }
#pragma unroll
  for (int i = 0; i < 4; i++) {
    float4v r;
#pragma unroll
    for (int j = 0; j < 4; j++) r[j] = acc[i][j] * scale;
    *(float4v*)&D[(ty * 4 + i) * 68 + tx * 4] = r;
  }
}

// ---------- pinv (Newton-Schulz, fp32, fused diag-sub) + z2 = a2inv @ z1 ----------
__global__ __launch_bounds__(256) void k_pinv(
    const float* __restrict__ a2g, const float* __restrict__ Zp,
    const float* __restrict__ dp, const float* __restrict__ scalars,
    u16* __restrict__ z2t) {
  __shared__ float A2[64*68], B1[64*68], B2[64*68], B3[64*68], B4[64*68], Z1[64*68];
  __shared__ float dsum[64];
  int bh = blockIdx.x, tid = threadIdx.x;
  for (int e4 = tid; e4 < 1024; e4 += 256) {
    int idx = e4 * 4, r = idx >> 6, c = idx & 63;
    float4v a = *(const float4v*)(a2g + (size_t)bh * 4096 + idx);
    *(float4v*)&A2[r * 68 + c] = a;
    float4v s = {0.f, 0.f, 0.f, 0.f};
    for (int ch = 0; ch < 16; ch++) {
      float4v z = *(const float4v*)(Zp + ((size_t)ch * 64 + bh) * 4096 + idx);
      s[0] += z[0]; s[1] += z[1]; s[2] += z[2]; s[3] += z[3];
    }
    *(float4v*)&Z1[r * 68 + c] = s;
  }
  if (tid < 64) {
    float s = 0.f;
    for (int c = 0; c < 16; c++) s += dp[((size_t)c * 64 + bh) * 64 + tid];
    dsum[tid] = 1.f / s;
  }
  __syncthreads();
  float cinv = 1.f / (scalars[0] * scalars[1]);
  for (int e = tid; e < 4096; e += 256) {
    int r = e >> 6, c = e & 63;
    B1[c * 68 + r] = A2[r * 68 + c] * cinv;   // z0 = a2^T / (maxcol*maxrow)
    Z1[r * 68 + c] *= dsum[r];                // normalize a3v rows
  }
  __syncthreads();
  float *Zc = B1, *Sc = B2;
  for (int it = 0; it < 6; it++) {
    mm64x<0>(Sc, A2, Zc, tid, 0.f, 1.f);   __syncthreads();
    mm64x<1>(B3, Sc, Sc, tid, 7.f, 1.f);   __syncthreads();
    mm64x<1>(B4, Sc, B3, tid, 15.f, 1.f);  __syncthreads();
    mm64x<1>(Sc, Zc, B4, tid, 13.f, 0.25f); __syncthreads();
    float* t = Zc; Zc = Sc; Sc = t;
  }
  mm64x<0>(B3, Zc, Z1, tid, 0.f, 1.f);
  __syncthreads();
  for (int e = tid; e < 4096; e += 256) {
    int m = e >> 6, d = e & 63;
    z2t[((size_t)bh * 64 + d) * 64 + m] = f2bf(B3[m * 68 + d]);
  }
}

// ---------- a1 = softmax(q k_land^T); out = a1 @ z2 + depthwise-conv(v); write bf16 ----------
__global__ __launch_bounds__(256) void k_comb(
    const u16* __restrict__ qb, const u16* __restrict__ klb, const u16* __restrict__ z2t,
    const u16* __restrict__ vt, const float* __restrict__ Wc,
    u16* __restrict__ attn) {
  __shared__ u16 Ps[128 * 64];
  __shared__ float wpad[80];
  int bh = blockIdx.x, nt = blockIdx.y;
  int b = bh >> 4, h = bh & 15;
  int n0 = nt * 128;
  int tid = threadIdx.x, w = tid >> 6, l = tid & 63;
  int lr = l & 15, lk = (l >> 4) * 8;
  if (tid < 80) {
    int t = tid - 16;
    wpad[tid] = (t >= 0 && t < 33) ? Wc[h * 33 + t] : 0.f;
  }
  f32x4 zero = {0.f,0.f,0.f,0.f};
  f32x4 sa[2][4];
#pragma unroll
  for (int i = 0; i < 2; i++)
#pragma unroll
    for (int j = 0; j < 4; j++) sa[i][j] = zero;
  const u16* qbase = qb + ((size_t)bh * 4096 + n0 + w * 32) * 64;
  const u16* kbase = klb + (size_t)bh * 4096;
#pragma unroll
  for (int ks = 0; ks < 2; ks++) {
    bf16x8 af[2], bfr[4];
#pragma unroll
    for (int i = 0; i < 2; i++)
      af[i] = *(const bf16x8*)(qbase + (size_t)(i * 16 + lr) * 64 + ks * 32 + lk);
#pragma unroll
    for (int j = 0; j < 4; j++)
      bfr[j] = *(const bf16x8*)(kbase + (size_t)(j * 16 + lr) * 64 + ks * 32 + lk);
#pragma unroll
    for (int i = 0; i < 2; i++)
#pragma unroll
      for (int j = 0; j < 4; j++)
        sa[i][j] = __builtin_amdgcn_mfma_f32_16x16x32_bf16(af[i], bfr[j], sa[i][j], 0, 0, 0);
  }
#pragma unroll
  for (int i = 0; i < 2; i++)
#pragma unroll
    for (int r = 0; r < 4; r++) {
      float e0 = __expf(sa[i][0][r]);
      float e1 = __expf(sa[i][1][r]);
      float e2 = __expf(sa[i][2][r]);
      float e3 = __expf(sa[i][3][r]);
      float rsum = e0 + e1 + e2 + e3;
      rsum += __shfl_xor(rsum, 1);
      rsum += __shfl_xor(rsum, 2);
      rsum += __shfl_xor(rsum, 4);
      rsum += __shfl_xor(rsum, 8);
      float inv = 1.f / rsum;
      int nl = w * 32 + i * 16 + (l >> 4) * 4 + r;
      int m0 = lr, m1 = 16 + lr, m2 = 32 + lr, m3 = 48 + lr;
      Ps[nl * 64 + ((m0 >> 3) ^ (nl & 7)) * 8 + (m0 & 7)] = f2bf(e0 * inv);
      Ps[nl * 64 + ((m1 >> 3) ^ (nl & 7)) * 8 + (m1 & 7)] = f2bf(e1 * inv);
      Ps[nl * 64 + ((m2 >> 3) ^ (nl & 7)) * 8 + (m2 & 7)] = f2bf(e2 * inv);
      Ps[nl * 64 + ((m3 >> 3) ^ (nl & 7)) * 8 + (m3 & 7)] = f2bf(e3 * inv);
    }
  __syncthreads();

  bf16x8 whi[2], wlo[2];
#pragma unroll
  for (int s = 0; s < 2; s++)
#pragma unroll
    for (int e = 0; e < 8; e++) {
      int idx = 16 + s * 32 + lk + e - lr;
      float wv = wpad[idx];
      u16 hi = f2bf(wv);
      float lof = wv - bf2f(hi);
      whi[s][e] = (short)hi;
      wlo[s][e] = (short)f2bf(lof);
    }

  f32x4 oa[2][4];
#pragma unroll
  for (int i = 0; i < 2; i++)
#pragma unroll
    for (int j = 0; j < 4; j++) oa[i][j] = zero;

#pragma unroll
  for (int i = 0; i < 2; i++) {
    int base_i = n0 + w * 32 + i * 16;
#pragma unroll
    for (int dj = 0; dj < 4; dj++) {
      const u16* vrow = vt + ((size_t)bh * 64 + dj * 16 + lr) * VT_STRIDE + base_i + lk;
#pragma unroll
      for (int s = 0; s < 2; s++) {
        bf16x8 bv = *(const bf16x8*)(vrow + s * 32);
        oa[i][dj] = __builtin_amdgcn_mfma_f32_16x16x32_bf16(whi[s], bv, oa[i][dj], 0, 0, 0);
        oa[i][dj] = __builtin_amdgcn_mfma_f32_16x16x32_bf16(wlo[s], bv, oa[i][dj], 0, 0, 0);
      }
    }
  }

  const u16* zb = z2t + (size_t)bh * 4096;
#pragma unroll
  for (int ks = 0; ks < 2; ks++) {
    bf16x8 af[2], bfr[4];
#pragma unroll
    for (int i = 0; i < 2; i++) {
      int row = w * 32 + i * 16 + lr;
      int kk = ks * 32 + lk;
      af[i] = *(const bf16x8*)&Ps[row * 64 + ((kk >> 3) ^ (row & 7)) * 8];
    }
#pragma unroll
    for (int j = 0; j < 4; j++)
      bfr[j] = *(const bf16x8*)(zb + (size_t)(j * 16 + lr) * 64 + ks * 32 + lk);
#pragma unroll
    for (int i = 0; i < 2; i++)
#pragma unroll
      for (int j = 0; j < 4; j++)
        oa[i][j] = __builtin_amdgcn_mfma_f32_16x16x32_bf16(af[i], bfr[j], oa[i][j], 0, 0, 0);
  }
#pragma unroll
  for (int i = 0; i < 2; i++)
#pragma unroll
    for (int dj = 0; dj < 4; dj++)
#pragma unroll
      for (int r = 0; r < 4; r++) {
        int n = n0 + w * 32 + i * 16 + (l >> 4) * 4 + r;
        int d = dj * 16 + lr;
        size_t idx = ((size_t)b * 4096 + n) * 1024 + h * 64 + d;
        attn[idx] = f2bf(oa[i][dj][r]);
      }
}

// =======================================================================
extern "C" void kernel_launch(void* const* d_in, const int* in_sizes, int n_in,
                              void* d_out, int out_size, void* d_ws, size_t ws_size,
                              hipStream_t stream) {
  const float* x  = (const float*)d_in[0];
  const float* Wq = (const float*)d_in[1];
  const float* Wk = (const float*)d_in[2];
  const float* Wv = (const float*)d_in[3];
  const float* Wo = (const float*)d_in[4];
  const float* Wc = (const float*)d_in[5];
  float* out = (float*)d_out;

  char* p = (char*)d_ws;
  auto alloc = [&](size_t bytes) { char* r = p; p += (bytes + 255) & ~(size_t)255; return r; };
  const size_t TOK = 16384ull * 1024;
  u16*  xb   = (u16*)alloc(TOK * 2);          // x bf16; later reused as attn buffer
  u16*  qb   = (u16*)alloc(TOK * 2);
  u16*  kb   = (u16*)alloc(TOK * 2);
  u16*  vt   = (u16*)alloc(64ull * 64 * VT_STRIDE * 2);
  u16*  wall = (u16*)alloc(4096ull * 1024 * 2);   // [Wq;Wk;Wv;Wo] stacked bf16
  float* xlp = (float*)alloc(2ull * 256 * 1024 * 4);   // two 32-row partial sums
  float* ql  = (float*)alloc(64ull * 4096 * 4);
  float* kl  = (float*)alloc(64ull * 4096 * 4);
  u16*  qlb  = (u16*)alloc(64ull * 4096 * 2);
  u16*  klb  = (u16*)alloc(64ull * 4096 * 2);
  float* a2b = (float*)alloc(64ull * 4096 * 4);
  float* Zp  = (float*)alloc(16ull * 64 * 4096 * 4);
  float* dp  = (float*)alloc(16ull * 64 * 64 * 4);
  u16*  z2tb = (u16*)alloc(64ull * 4096 * 2);
  float* scl = (float*)alloc(256);
  (void)ws_size; (void)in_sizes; (void)n_in; (void)out_size;

  k_prep<<<4672, 256, 0, stream>>>(x, xb, xlp, scl, Wq, Wk, Wv, Wo, wall, vt);

  // QKV: M=16384, N=3072 -> 64 x 12 tiles = 768 blocks; v lands transposed in vt
  k_gemm256<0><<<768, 1024, 0, stream>>>(xb, wall, qb, kb, vt, nullptr, 12);

  k_landproj<<<dim3(4, 32, 2), 256, 0, stream>>>(xlp, Wq, Wk, ql, kl, qlb, klb);
  k_a3a2<<<dim3(64, 17), 256, 0, stream>>>(qlb, kb, vt, Zp, dp, ql, kl, a2b, scl);
  k_pinv<<<64, 256, 0, stream>>>(a2b, Zp, dp, scl, z2tb);

  k_comb<<<dim3(64, 32), 256, 0, stream>>>(qb, klb, z2tb, vt, Wc, xb);
  // out-proj: M=16384, N=1024 -> 64 x 4 tiles = 256 blocks
  k_gemm256<1><<<256, 1024, 0, stream>>>(xb, wall + 3ull * 1048576, nullptr, nullptr, nullptr, out, 4);
}

// Round 16
// 334.950 us; speedup vs baseline: 1.2103x; 1.2103x over previous
//
#include <hip/hip_runtime.h>

typedef unsigned short u16;
typedef __attribute__((ext_vector_type(4))) float float4v;
typedef __attribute__((ext_vector_type(4))) unsigned short ushort4v;
typedef __attribute__((ext_vector_type(8))) unsigned short ushort8v;
typedef __attribute__((ext_vector_type(8))) short bf16x8;
typedef __attribute__((ext_vector_type(4))) float f32x4;

#define DEV static __device__ __forceinline__

#define VT_STRIDE 4144   // 16 left pad + 4096 + 32 right pad

DEV u16 f2bf(float f) {
  unsigned u = __float_as_uint(f);
  u += 0x7fffu + ((u >> 16) & 1u);
  return (u16)(u >> 16);
}
DEV float bf2f(u16 h) { return __uint_as_float(((unsigned)h) << 16); }

DEV void gload16(const void* g, void* l) {
  __builtin_amdgcn_global_load_lds((const __attribute__((address_space(1))) unsigned int*)g,
                                   (__attribute__((address_space(3))) unsigned int*)l, 16, 0, 0);
}

// ---------- merged prep: x cvt+landmark partials | W cvt | vt pad borders ----------
__global__ __launch_bounds__(256) void k_prep(
    const float* __restrict__ x, u16* __restrict__ xb, float* __restrict__ xlp,
    float* __restrict__ scl,
    const float* __restrict__ Wq, const float* __restrict__ Wk,
    const float* __restrict__ Wv, const float* __restrict__ Wo,
    u16* __restrict__ wall, u16* __restrict__ vt) {
  int blk = blockIdx.x;
  if (blk < 512) {
    int bm = blk >> 1, half = blk & 1;
    if (blk == 0 && threadIdx.x == 0) { scl[0] = 0.f; scl[1] = 0.f; }
    int d0 = threadIdx.x * 4;
    const float* base = x + (size_t)bm * 65536 + (size_t)half * 32768 + d0;
    u16* ob = xb + (size_t)bm * 65536 + (size_t)half * 32768 + d0;
    float4v s0 = {0.f, 0.f, 0.f, 0.f}, s1 = {0.f, 0.f, 0.f, 0.f};
#pragma unroll 8
    for (int n = 0; n < 32; n += 2) {
      float4v v0 = *(const float4v*)(base + n * 1024);
      float4v v1 = *(const float4v*)(base + (n + 1) * 1024);
      s0 += v0;
      s1 += v1;
      ushort4v o0, o1;
#pragma unroll
      for (int e = 0; e < 4; e++) { o0[e] = f2bf(v0[e]); o1[e] = f2bf(v1[e]); }
      *(ushort4v*)(ob + n * 1024) = o0;
      *(ushort4v*)(ob + (n + 1) * 1024) = o1;
    }
    float4v m = s0 + s1;
    *(float4v*)(xlp + ((size_t)half * 256 + bm) * 1024 + d0) = m;
  } else if (blk < 4608) {
    int gtid = (blk - 512) * 256 + threadIdx.x;
    int which = gtid >> 18;
    int off = (gtid & 262143) * 4;
    const float* s = which == 0 ? Wq : (which == 1 ? Wk : (which == 2 ? Wv : Wo));
    float4v v = *(const float4v*)(s + off);
    ushort4v o;
    o[0] = f2bf(v[0]); o[1] = f2bf(v[1]); o[2] = f2bf(v[2]); o[3] = f2bf(v[3]);
    *(ushort4v*)(wall + (size_t)which * 1048576 + off) = o;
  } else {
    int bh = blk - 4608, t = threadIdx.x;
    ushort8v zz = {0,0,0,0,0,0,0,0};
    if (t < 64) {
      u16* z = vt + ((size_t)bh * 64 + t) * VT_STRIDE;
      *(ushort8v*)z = zz; *(ushort8v*)(z + 8) = zz;
    } else if (t < 128) {
      u16* z = vt + ((size_t)bh * 64 + (t - 64)) * VT_STRIDE + 4112;
      *(ushort8v*)z = zz; *(ushort8v*)(z + 8) = zz;
      *(ushort8v*)(z + 16) = zz; *(ushort8v*)(z + 24) = zz;
    }
  }
}

// ---------- 256x256-tile bf16 GEMM, 8-phase (T2+T3+T4+T5), 16x16x32 MFMA ----------
// C[row,col] = sum_k A[row,k]*Bt[col,k], K=1024, BK=64, 8 waves (2M x 4N).
// Per phase: {ds_read subtile; stage 1 half-tile; lgkmcnt(0); setprio 16xMFMA; barrier}.
// Counted vmcnt(4) only at ph0/ph4. Swizzle LDS[row][c16]=global[c16^(row&7)] (0-conflict).
// MODE 0: Bt=[Wq;Wk;Wv]; q,k scattered bf16 [b,h,n,hd] (q/8); v TRANSPOSED into padded vt.
// MODE 1: Bt=Wo; fp32 linear [row*1024+col].
template<int MODE>
__global__ __launch_bounds__(512, 2) void k_gemm256(
    const u16* __restrict__ A, const u16* __restrict__ Bt,
    u16* __restrict__ oq, u16* __restrict__ ok, u16* __restrict__ ovt,
    float* __restrict__ outf, int NBN) {
  __shared__ u16 smem[65536];          // A: [0,32768) u16, B: [32768,65536)
  const int K = 1024;
  const int tid = threadIdx.x;
  const int w = tid >> 6, l = tid & 63;
  const int lr = l & 15;               // fragment row within 16
  const int lg = l >> 4;               // k-subgroup 0..3

  // XCD-bijective block swizzle (nwg % 8 == 0 for all our launches)
  const int nwg = gridDim.x;
  const int q8 = nwg >> 3;
  const int wg = ((int)blockIdx.x & 7) * q8 + ((int)blockIdx.x >> 3);
  const int bn = wg % NBN, bm = wg / NBN;
  const int wm = w >> 2, wn = w & 3;   // wave tile: rows wm*128, cols wn*64

  // staging source swizzle (inverse of read-side; row&7 = l>>3)
  const int srow = l >> 3;
  const int scol = ((l & 7) ^ srow) * 8;

  auto stageA = [&](int d, int h, int t) {
    const u16* g = A + (size_t)(bm * 256 + h * 128 + w * 8 + srow) * K + t * 64 + scol;
    u16* ldst = smem + (d * 2 + h) * 8192 + w * 512;
    gload16(g, ldst);
    gload16(g + (size_t)64 * K, ldst + 4096);
  };
  auto stageB = [&](int d, int h, int t) {
    const u16* g = Bt + (size_t)(bn * 256 + h * 128 + w * 8 + srow) * K + t * 64 + scol;
    u16* ldst = smem + 32768 + (d * 2 + h) * 8192 + w * 512;
    gload16(g, ldst);
    gload16(g + (size_t)64 * K, ldst + 4096);
  };
  auto rdA = [&](int d, int mf, int ks) -> bf16x8 {
    return *(const bf16x8*)(smem + d * 16384 + wm * 8192
                            + (mf * 16 + lr) * 64 + (((ks * 4 + lg) ^ (lr & 7)) << 3));
  };
  auto rdB = [&](int d, int nf, int ks) -> bf16x8 {
    return *(const bf16x8*)(smem + 32768 + d * 16384 + (wn >> 1) * 8192
                            + ((wn & 1) * 64 + nf * 16 + lr) * 64 + (((ks * 4 + lg) ^ (lr & 7)) << 3));
  };

  f32x4 acc[8][4];
  f32x4 zero = {0.f, 0.f, 0.f, 0.f};
#pragma unroll
  for (int i = 0; i < 8; i++)
#pragma unroll
    for (int j = 0; j < 4; j++) acc[i][j] = zero;

#define PH_MFMA(MBASE, NBASE)                                                        \
    asm volatile("s_waitcnt lgkmcnt(0)" ::: "memory");                               \
    __builtin_amdgcn_sched_barrier(0);                                               \
    __builtin_amdgcn_s_setprio(1);                                                   \
    _Pragma("unroll")                                                                \
    for (int ks = 0; ks < 2; ks++)                                                   \
      _Pragma("unroll")                                                              \
      for (int mi = 0; mi < 4; mi++)                                                 \
        _Pragma("unroll")                                                            \
        for (int nj = 0; nj < 2; nj++)                                               \
          acc[(MBASE) + mi][(NBASE) + nj] = __builtin_amdgcn_mfma_f32_16x16x32_bf16( \
              af[mi][ks], bfr[(NBASE) + nj][ks], acc[(MBASE) + mi][(NBASE) + nj], 0, 0, 0); \
    __builtin_amdgcn_s_setprio(0);                                                   \
    __builtin_amdgcn_s_barrier();

  stageB(0, 0, 0); stageB(0, 1, 0);
  stageA(0, 0, 0); stageA(0, 1, 0);
  stageB(1, 0, 1); stageB(1, 1, 1);

  bf16x8 af[4][2], bfr[4][2];
  for (int u = 0; u < 8; u++) {
    const int t1 = 2 * u + 1;
    // ---- ph0: tile t0, quadrant (mf0-3 x nf0-1) ----
    asm volatile("s_waitcnt vmcnt(4)" ::: "memory");
    __builtin_amdgcn_s_barrier();
#pragma unroll
    for (int ks = 0; ks < 2; ks++) {
#pragma unroll
      for (int mi = 0; mi < 4; mi++) af[mi][ks] = rdA(0, mi, ks);
#pragma unroll
      for (int nj = 0; nj < 2; nj++) bfr[nj][ks] = rdB(0, nj, ks);
    }
    stageA(1, 0, t1);
    PH_MFMA(0, 0)
    // ---- ph1 ----
#pragma unroll
    for (int ks = 0; ks < 2; ks++)
#pragma unroll
      for (int nj = 0; nj < 2; nj++) bfr[2 + nj][ks] = rdB(0, 2 + nj, ks);
    stageA(1, 1, t1);
    PH_MFMA(0, 2)
    // ---- ph2 ----
#pragma unroll
    for (int ks = 0; ks < 2; ks++)
#pragma unroll
      for (int mi = 0; mi < 4; mi++) af[mi][ks] = rdA(0, 4 + mi, ks);
    if (u < 7) stageB(0, 0, 2 * u + 2);
    PH_MFMA(4, 2)
    // ---- ph3 ----
    if (u < 7) stageB(0, 1, 2 * u + 2);
    PH_MFMA(4, 0)
    // ---- ph4: tile t1 ----
    if (u < 7) asm volatile("s_waitcnt vmcnt(4)" ::: "memory");
    else       asm volatile("s_waitcnt vmcnt(0)" ::: "memory");
    __builtin_amdgcn_s_barrier();
#pragma unroll
    for (int ks = 0; ks < 2; ks++) {
#pragma unroll
      for (int mi = 0; mi < 4; mi++) af[mi][ks] = rdA(1, mi, ks);
#pragma unroll
      for (int nj = 0; nj < 2; nj++) bfr[nj][ks] = rdB(1, nj, ks);
    }
    if (u < 7) stageA(0, 0, 2 * u + 2);
    PH_MFMA(0, 0)
    // ---- ph5 ----
#pragma unroll
    for (int ks = 0; ks < 2; ks++)
#pragma unroll
      for (int nj = 0; nj < 2; nj++) bfr[2 + nj][ks] = rdB(1, 2 + nj, ks);
    if (u < 7) stageA(0, 1, 2 * u + 2);
    PH_MFMA(0, 2)
    // ---- ph6 ----
#pragma unroll
    for (int ks = 0; ks < 2; ks++)
#pragma unroll
      for (int mi = 0; mi < 4; mi++) af[mi][ks] = rdA(1, 4 + mi, ks);
    if (u < 7) stageB(1, 0, 2 * u + 3);
    PH_MFMA(4, 2)
    // ---- ph7 ----
    if (u < 7) stageB(1, 1, 2 * u + 3);
    PH_MFMA(4, 0)
  }
#undef PH_MFMA

  // epilogue: 16x16 C/D layout: col = lr, row = lg*4 + r
#pragma unroll
  for (int mf = 0; mf < 8; mf++)
#pragma unroll
    for (int nf = 0; nf < 4; nf++) {
      int col  = bn * 256 + wn * 64 + nf * 16 + lr;
      int row0 = bm * 256 + wm * 128 + mf * 16 + lg * 4;
      if (MODE == 1) {
#pragma unroll
        for (int r = 0; r < 4; r++)
          outf[(size_t)(row0 + r) * 1024 + col] = acc[mf][nf][r];
      } else {
        int which = col >> 10;
        int c2 = col & 1023;
        int h = c2 >> 6, hd = c2 & 63;
        if (which == 2) {
          int b = row0 >> 12, nn = row0 & 4095;
          ushort4v pk;
#pragma unroll
          for (int r = 0; r < 4; r++) pk[r] = f2bf(acc[mf][nf][r]);
          *(ushort4v*)(ovt + ((size_t)(b * 16 + h) * 64 + hd) * VT_STRIDE + 16 + nn) = pk;
        } else {
          u16* o = which == 0 ? oq : ok;
          float sc = which == 0 ? 0.125f : 1.f;   // q /= tau = 8
#pragma unroll
          for (int r = 0; r < 4; r++) {
            int row = row0 + r;
            int b = row >> 12, n = row & 4095;
            o[(((size_t)(b * 16 + h)) * 4096 + n) * 64 + hd] = f2bf(acc[mf][nf][r] * sc);
          }
        }
      }
    }
}

// ---------- fp32 landmark projections: ql/kl = mean(x) @ W^T (tiled LDS fp32 GEMM) ----------
__global__ __launch_bounds__(256) void k_landproj(
    const float* __restrict__ xlp,
    const float* __restrict__ Wq, const float* __restrict__ Wk,
    float* __restrict__ ql, float* __restrict__ kl,
    u16* __restrict__ qlb, u16* __restrict__ klb) {
  __shared__ float As[64][68];
  __shared__ float Bs[32][68];
  const int rb = blockIdx.x * 64;
  const int jb = blockIdx.y * 32;
  const int wz = blockIdx.z;
  const float* __restrict__ W = wz ? Wk : Wq;
  const int tid = threadIdx.x;
  const int ty = tid >> 4, tx = tid & 15;
  const int lrow = tid >> 4;
  const int lcol = (tid & 15) * 4;
  float acc[4][2] = {{0.f,0.f},{0.f,0.f},{0.f,0.f},{0.f,0.f}};

  for (int kt = 0; kt < 1024; kt += 64) {
#pragma unroll
    for (int i = 0; i < 4; i++) {
      size_t rbase = (size_t)(rb + lrow + i * 16) * 1024 + kt + lcol;
      float4v v0 = *(const float4v*)(xlp + rbase);
      float4v v1 = *(const float4v*)(xlp + 262144 + rbase);
      float4v v = (v0 + v1) * 0.015625f;   // mean over 64 rows
      *(float4v*)&As[lrow + i * 16][lcol] = v;
    }
#pragma unroll
    for (int i = 0; i < 2; i++) {
      float4v v = *(const float4v*)(W + (size_t)(jb + lrow + i * 16) * 1024 + kt + lcol);
      *(float4v*)&Bs[lrow + i * 16][lcol] = v;
    }
    __syncthreads();
#pragma unroll
    for (int k = 0; k < 64; k += 4) {
      float4v a0 = *(const float4v*)&As[ty * 4 + 0][k];
      float4v a1 = *(const float4v*)&As[ty * 4 + 1][k];
      float4v a2 = *(const float4v*)&As[ty * 4 + 2][k];
      float4v a3 = *(const float4v*)&As[ty * 4 + 3][k];
      float4v b0 = *(const float4v*)&Bs[tx * 2 + 0][k];
      float4v b1 = *(const float4v*)&Bs[tx * 2 + 1][k];
#pragma unroll
      for (int e = 0; e < 4; e++) {
        acc[0][0] += a0[e] * b0[e]; acc[0][1] += a0[e] * b1[e];
        acc[1][0] += a1[e] * b0[e]; acc[1][1] += a1[e] * b1[e];
        acc[2][0] += a2[e] * b0[e]; acc[2][1] += a2[e] * b1[e];
        acc[3][0] += a3[e] * b0[e]; acc[3][1] += a3[e] * b1[e];
      }
    }
    __syncthreads();
  }

  const float s = wz ? 1.f : 0.125f;   // q /= tau = 8
#pragma unroll
  for (int i = 0; i < 4; i++) {
    int row = rb + ty * 4 + i;          // b*64+m
    int b = row >> 6, m = row & 63;
#pragma unroll
    for (int j = 0; j < 2; j++) {
      int col = jb + tx * 2 + j;        // h*64+hd
      int h = col >> 6, hd = col & 63;
      size_t idx = (((size_t)(b * 16 + h)) * 64 + m) * 64 + hd;
      float v = acc[i][j] * s;
      if (wz) { kl[idx] = v; klb[idx] = f2bf(v); }
      else    { ql[idx] = v; qlb[idx] = f2bf(v); }
    }
  }
}

// ---------- merged: a3@v partials (ch 0..15) | a2 softmax + scalars (ch 16) ----------
__global__ __launch_bounds__(256) void k_a3a2(
    const u16* __restrict__ qlb, const u16* __restrict__ kb, const u16* __restrict__ vt,
    float* __restrict__ Zp, float* __restrict__ dp,
    const float* __restrict__ ql, const float* __restrict__ kl,
    float* __restrict__ a2g, float* __restrict__ scalars) {
  __shared__ float smf[3 * 64 * 68];
  int bh = blockIdx.x, ch = blockIdx.y;
  int tid = threadIdx.x;

  if (ch == 16) {
    float* qs = smf;
    float* ksm = smf + 64 * 68;
    float* ss = smf + 2 * 64 * 68;
    for (int e = tid; e < 4096; e += 256) {
      int r = e >> 6, c = e & 63;
      qs[r * 68 + c]  = ql[(size_t)bh * 4096 + e];
      ksm[r * 68 + c] = kl[(size_t)bh * 4096 + e];
    }
    __syncthreads();
    int ty = tid >> 4, tx = tid & 15;
    float acc[4][4];
#pragma unroll
    for (int i = 0; i < 4; i++)
#pragma unroll
      for (int j = 0; j < 4; j++) acc[i][j] = 0.f;
    for (int d = 0; d < 64; d++) {
      float a0 = qs[(ty*4+0)*68+d], a1 = qs[(ty*4+1)*68+d];
      float a2v = qs[(ty*4+2)*68+d], a3v = qs[(ty*4+3)*68+d];
      float b0 = ksm[(tx*4+0)*68+d], b1 = ksm[(tx*4+1)*68+d];
      float b2 = ksm[(tx*4+2)*68+d], b3 = ksm[(tx*4+3)*68+d];
      acc[0][0]+=a0*b0; acc[0][1]+=a0*b1; acc[0][2]+=a0*b2; acc[0][3]+=a0*b3;
      acc[1][0]+=a1*b0; acc[1][1]+=a1*b1; acc[1][2]+=a1*b2; acc[1][3]+=a1*b3;
      acc[2][0]+=a2v*b0; acc[2][1]+=a2v*b1; acc[2][2]+=a2v*b2; acc[2][3]+=a2v*b3;
      acc[3][0]+=a3v*b0; acc[3][1]+=a3v*b1; acc[3][2]+=a3v*b2; acc[3][3]+=a3v*b3;
    }
#pragma unroll
    for (int i = 0; i < 4; i++)
#pragma unroll
      for (int j = 0; j < 4; j++)
        ss[(ty*4+i)*68 + tx*4 + j] = acc[i][j];
    __syncthreads();
    if (tid < 64) {
      float sum = 0.f;
      for (int j = 0; j < 64; j++) {
        float e = __expf(ss[tid * 68 + j]);
        ss[tid * 68 + j] = e; sum += e;
      }
      float inv = 1.f / sum;
      for (int j = 0; j < 64; j++) {
        float p = ss[tid * 68 + j] * inv;
        ss[tid * 68 + j] = p;
        a2g[(size_t)bh * 4096 + tid * 64 + j] = p;
      }
    }
    __syncthreads();
    if (tid < 64) {
      float cs = 0.f, rs = 0.f;
      for (int r = 0; r < 64; r++) cs += ss[r * 68 + tid];
      for (int j = 0; j < 64; j++) rs += ss[tid * 68 + j];
      for (int msk = 1; msk < 64; msk <<= 1) {
        cs = fmaxf(cs, __shfl_xor(cs, msk));
        rs = fmaxf(rs, __shfl_xor(rs, msk));
      }
      if (tid == 0) {
        atomicMax((unsigned int*)&scalars[0], __float_as_uint(rs));
        atomicMax((unsigned int*)&scalars[1], __float_as_uint(cs));
      }
    }
    return;
  }

  u16* Ps = (u16*)smf;
  float* denom_s = smf + 8192;
  int n0 = ch * 256;
  int w = tid >> 6, l = tid & 63;
  int lr = l & 15, lk = (l >> 4) * 8;
  if (tid < 64) denom_s[tid] = 0.f;
  __syncthreads();
  f32x4 zero = {0.f,0.f,0.f,0.f};
  f32x4 sa[4][4];
#pragma unroll
  for (int i = 0; i < 4; i++)
#pragma unroll
    for (int j = 0; j < 4; j++) sa[i][j] = zero;
  const u16* qbase = qlb + (size_t)bh * 4096;
  const u16* kbase = kb + ((size_t)bh * 4096 + n0 + w * 64) * 64;
#pragma unroll
  for (int ks = 0; ks < 2; ks++) {
    bf16x8 af[4], bfr[4];
#pragma unroll
    for (int i = 0; i < 4; i++) {
      af[i]  = *(const bf16x8*)(qbase + (size_t)(i * 16 + lr) * 64 + ks * 32 + lk);
      bfr[i] = *(const bf16x8*)(kbase + (size_t)(i * 16 + lr) * 64 + ks * 32 + lk);
    }
#pragma unroll
    for (int i = 0; i < 4; i++)
#pragma unroll
      for (int j = 0; j < 4; j++)
        sa[i][j] = __builtin_amdgcn_mfma_f32_16x16x32_bf16(af[i], bfr[j], sa[i][j], 0, 0, 0);
  }
#pragma unroll
  for (int i = 0; i < 4; i++) {
#pragma unroll
    for (int r = 0; r < 4; r++) {
      int m = i * 16 + (l >> 4) * 4 + r;
      float rsum = 0.f;
#pragma unroll
      for (int j = 0; j < 4; j++) {
        float p = __expf(sa[i][j][r]);
        rsum += p;
        int n = w * 64 + j * 16 + lr;
        Ps[m * 256 + ((n >> 3) ^ (m & 7)) * 8 + (n & 7)] = f2bf(p);
      }
      rsum += __shfl_xor(rsum, 1);
      rsum += __shfl_xor(rsum, 2);
      rsum += __shfl_xor(rsum, 4);
      rsum += __shfl_xor(rsum, 8);
      if (lr == 0) atomicAdd(&denom_s[m], rsum);
    }
  }
  __syncthreads();
  if (tid < 64) dp[((size_t)ch * 64 + bh) * 64 + tid] = denom_s[tid];
  f32x4 oa[4];
#pragma unroll
  for (int i = 0; i < 4; i++) oa[i] = zero;
  const u16* vtb = vt + ((size_t)bh * 64 + w * 16 + lr) * VT_STRIDE + 16 + n0;
#pragma unroll
  for (int ks = 0; ks < 8; ks++) {
    bf16x8 bv = *(const bf16x8*)(vtb + ks * 32 + lk);
#pragma unroll
    for (int i = 0; i < 4; i++) {
      int row = i * 16 + lr;
      int kk = ks * 32 + lk;
      bf16x8 af = *(const bf16x8*)&Ps[row * 256 + ((kk >> 3) ^ (row & 7)) * 8];
      oa[i] = __builtin_amdgcn_mfma_f32_16x16x32_bf16(af, bv, oa[i], 0, 0, 0);
    }
  }
#pragma unroll
  for (int i = 0; i < 4; i++)
#pragma unroll
    for (int r = 0; r < 4; r++) {
      int m = i * 16 + (l >> 4) * 4 + r;
      int d = w * 16 + lr;
      Zp[(((size_t)ch * 64 + bh) * 64 + m) * 64 + d] = oa[i][r];
    }
}

// ---------- fp32 64x64 matmul in LDS (stride 68), float4 both operands ----------
template<int NEGB>
DEV void mm64x(float* __restrict__ D, const float* A, const float* B, int tid,
               float cB, float scale) {
  int ty = tid >> 4, tx = tid & 15;
  float acc[4][4];
#pragma unroll
  for (int i = 0; i < 4; i++)
#pragma unroll
    for (int j = 0; j < 4; j++) acc[i][j] = 0.f;
  const float* a0p = A + (ty * 4 + 0) * 68;
  const float* a1p = A + (ty * 4 + 1) * 68;
  const float* a2p = A + (ty * 4 + 2) * 68;
  const float* a3p = A + (ty * 4 + 3) * 68;
#pragma unroll 4
  for (int k = 0; k < 64; k += 4) {
    float4v av0 = *(const float4v*)(a0p + k);
    float4v av1 = *(const float4v*)(a1p + k);
    float4v av2 = *(const float4v*)(a2p + k);
    float4v av3 = *(const float4v*)(a3p + k);
    float4v b0 = *(const float4v*)&B[(k + 0) * 68 + tx * 4];
    float4v b1 = *(const float4v*)&B[(k + 1) * 68 + tx * 4];
    float4v b2 = *(const float4v*)&B[(k + 2) * 68 + tx * 4];
    float4v b3 = *(const float4v*)&B[(k + 3) * 68 + tx * 4];
    if (NEGB) {
      b0 = -b0; b1 = -b1; b2 = -b2; b3 = -b3;
      if (k == tx * 4) { b0[0] += cB; b1[1] += cB; b2[2] += cB; b3[3] += cB; }
    }
#pragma unroll
    for (int j = 0; j < 4; j++) {
      acc[0][j] = fmaf(av0[3], b3[j], fmaf(av0[2], b2[j], fmaf(av0[1], b1[j], fmaf(av0[0], b0[j], acc[0][j]))));
      acc[1][j] = fmaf(av1[3], b3[j], fmaf(av1[2], b2[j], fmaf(av1[1], b1[j], fmaf(av1[0], b0[j], acc[1][j]))));
      acc[2][j] = fmaf(av2[3], b3[j], fmaf(av2[2], b2[j], fmaf(av2[1], b1[j], fmaf(av2[0], b0[j], acc[2][j]))));
      acc[3][j] = fmaf(av3[3], b3[j], fmaf(av3[2], b2[j], fmaf(av3[1], b1[j], fmaf(av3[0], b0[j], acc[3][j]))));
    }
  }
#pragma unroll
  for (int i = 0; i < 4; i++) {
    float4v r;
#pragma unroll
    for (int j = 0; j < 4; j++) r[j] = acc[i][j] * scale;
    *(float4v*)&D[(ty * 4 + i) * 68 + tx * 4] = r;
  }
}

// ---------- pinv (Newton-Schulz, fp32, fused diag-sub) + z2 = a2inv @ z1 ----------
__global__ __launch_bounds__(256) void k_pinv(
    const float* __restrict__ a2g, const float* __restrict__ Zp,
    const float* __restrict__ dp, const float* __restrict__ scalars,
    u16* __restrict__ z2t) {
  __shared__ float A2[64*68], B1[64*68], B2[64*68], B3[64*68], B4[64*68], Z1[64*68];
  __shared__ float dsum[64];
  int bh = blockIdx.x, tid = threadIdx.x;
  for (int e4 = tid; e4 < 1024; e4 += 256) {
    int idx = e4 * 4, r = idx >> 6, c = idx & 63;
    float4v a = *(const float4v*)(a2g + (size_t)bh * 4096 + idx);
    *(float4v*)&A2[r * 68 + c] = a;
    float4v s = {0.f, 0.f, 0.f, 0.f};
    for (int ch = 0; ch < 16; ch++) {
      float4v z = *(const float4v*)(Zp + ((size_t)ch * 64 + bh) * 4096 + idx);
      s[0] += z[0]; s[1] += z[1]; s[2] += z[2]; s[3] += z[3];
    }
    *(float4v*)&Z1[r * 68 + c] = s;
  }
  if (tid < 64) {
    float s = 0.f;
    for (int c = 0; c < 16; c++) s += dp[((size_t)c * 64 + bh) * 64 + tid];
    dsum[tid] = 1.f / s;
  }
  __syncthreads();
  float cinv = 1.f / (scalars[0] * scalars[1]);
  for (int e = tid; e < 4096; e += 256) {
    int r = e >> 6, c = e & 63;
    B1[c * 68 + r] = A2[r * 68 + c] * cinv;   // z0 = a2^T / (maxcol*maxrow)
    Z1[r * 68 + c] *= dsum[r];                // normalize a3v rows
  }
  __syncthreads();
  float *Zc = B1, *Sc = B2;
  for (int it = 0; it < 6; it++) {
    mm64x<0>(Sc, A2, Zc, tid, 0.f, 1.f);   __syncthreads();
    mm64x<1>(B3, Sc, Sc, tid, 7.f, 1.f);   __syncthreads();
    mm64x<1>(B4, Sc, B3, tid, 15.f, 1.f);  __syncthreads();
    mm64x<1>(Sc, Zc, B4, tid, 13.f, 0.25f); __syncthreads();
    float* t = Zc; Zc = Sc; Sc = t;
  }
  mm64x<0>(B3, Zc, Z1, tid, 0.f, 1.f);
  __syncthreads();
  for (int e = tid; e < 4096; e += 256) {
    int m = e >> 6, d = e & 63;
    z2t[((size_t)bh * 64 + d) * 64 + m] = f2bf(B3[m * 68 + d]);
  }
}

// ---------- a1 = softmax(q k_land^T); out = a1 @ z2 + depthwise-conv(v); write bf16 ----------
__global__ __launch_bounds__(256) void k_comb(
    const u16* __restrict__ qb, const u16* __restrict__ klb, const u16* __restrict__ z2t,
    const u16* __restrict__ vt, const float* __restrict__ Wc,
    u16* __restrict__ attn) {
  __shared__ u16 Ps[128 * 64];
  __shared__ float wpad[80];
  int bh = blockIdx.x, nt = blockIdx.y;
  int b = bh >> 4, h = bh & 15;
  int n0 = nt * 128;
  int tid = threadIdx.x, w = tid >> 6, l = tid & 63;
  int lr = l & 15, lk = (l >> 4) * 8;
  if (tid < 80) {
    int t = tid - 16;
    wpad[tid] = (t >= 0 && t < 33) ? Wc[h * 33 + t] : 0.f;
  }
  f32x4 zero = {0.f,0.f,0.f,0.f};
  f32x4 sa[2][4];
#pragma unroll
  for (int i = 0; i < 2; i++)
#pragma unroll
    for (int j = 0; j < 4; j++) sa[i][j] = zero;
  const u16* qbase = qb + ((size_t)bh * 4096 + n0 + w * 32) * 64;
  const u16* kbase = klb + (size_t)bh * 4096;
#pragma unroll
  for (int ks = 0; ks < 2; ks++) {
    bf16x8 af[2], bfr[4];
#pragma unroll
    for (int i = 0; i < 2; i++)
      af[i] = *(const bf16x8*)(qbase + (size_t)(i * 16 + lr) * 64 + ks * 32 + lk);
#pragma unroll
    for (int j = 0; j < 4; j++)
      bfr[j] = *(const bf16x8*)(kbase + (size_t)(j * 16 + lr) * 64 + ks * 32 + lk);
#pragma unroll
    for (int i = 0; i < 2; i++)
#pragma unroll
      for (int j = 0; j < 4; j++)
        sa[i][j] = __builtin_amdgcn_mfma_f32_16x16x32_bf16(af[i], bfr[j], sa[i][j], 0, 0, 0);
  }
#pragma unroll
  for (int i = 0; i < 2; i++)
#pragma unroll
    for (int r = 0; r < 4; r++) {
      float e0 = __expf(sa[i][0][r]);
      float e1 = __expf(sa[i][1][r]);
      float e2 = __expf(sa[i][2][r]);
      float e3 = __expf(sa[i][3][r]);
      float rsum = e0 + e1 + e2 + e3;
      rsum += __shfl_xor(rsum, 1);
      rsum += __shfl_xor(rsum, 2);
      rsum += __shfl_xor(rsum, 4);
      rsum += __shfl_xor(rsum, 8);
      float inv = 1.f / rsum;
      int nl = w * 32 + i * 16 + (l >> 4) * 4 + r;
      int m0 = lr, m1 = 16 + lr, m2 = 32 + lr, m3 = 48 + lr;
      Ps[nl * 64 + ((m0 >> 3) ^ (nl & 7)) * 8 + (m0 & 7)] = f2bf(e0 * inv);
      Ps[nl * 64 + ((m1 >> 3) ^ (nl & 7)) * 8 + (m1 & 7)] = f2bf(e1 * inv);
      Ps[nl * 64 + ((m2 >> 3) ^ (nl & 7)) * 8 + (m2 & 7)] = f2bf(e2 * inv);
      Ps[nl * 64 + ((m3 >> 3) ^ (nl & 7)) * 8 + (m3 & 7)] = f2bf(e3 * inv);
    }
  __syncthreads();

  bf16x8 whi[2], wlo[2];
#pragma unroll
  for (int s = 0; s < 2; s++)
#pragma unroll
    for (int e = 0; e < 8; e++) {
      int idx = 16 + s * 32 + lk + e - lr;
      float wv = wpad[idx];
      u16 hi = f2bf(wv);
      float lof = wv - bf2f(hi);
      whi[s][e] = (short)hi;
      wlo[s][e] = (short)f2bf(lof);
    }

  f32x4 oa[2][4];
#pragma unroll
  for (int i = 0; i < 2; i++)
#pragma unroll
    for (int j = 0; j < 4; j++) oa[i][j] = zero;

#pragma unroll
  for (int i = 0; i < 2; i++) {
    int base_i = n0 + w * 32 + i * 16;
#pragma unroll
    for (int dj = 0; dj < 4; dj++) {
      const u16* vrow = vt + ((size_t)bh * 64 + dj * 16 + lr) * VT_STRIDE + base_i + lk;
#pragma unroll
      for (int s = 0; s < 2; s++) {
        bf16x8 bv = *(const bf16x8*)(vrow + s * 32);
        oa[i][dj] = __builtin_amdgcn_mfma_f32_16x16x32_bf16(whi[s], bv, oa[i][dj], 0, 0, 0);
        oa[i][dj] = __builtin_amdgcn_mfma_f32_16x16x32_bf16(wlo[s], bv, oa[i][dj], 0, 0, 0);
      }
    }
  }

  const u16* zb = z2t + (size_t)bh * 4096;
#pragma unroll
  for (int ks = 0; ks < 2; ks++) {
    bf16x8 af[2], bfr[4];
#pragma unroll
    for (int i = 0; i < 2; i++) {
      int row = w * 32 + i * 16 + lr;
      int kk = ks * 32 + lk;
      af[i] = *(const bf16x8*)&Ps[row * 64 + ((kk >> 3) ^ (row & 7)) * 8];
    }
#pragma unroll
    for (int j = 0; j < 4; j++)
      bfr[j] = *(const bf16x8*)(zb + (size_t)(j * 16 + lr) * 64 + ks * 32 + lk);
#pragma unroll
    for (int i = 0; i < 2; i++)
#pragma unroll
      for (int j = 0; j < 4; j++)
        oa[i][j] = __builtin_amdgcn_mfma_f32_16x16x32_bf16(af[i], bfr[j], oa[i][j], 0, 0, 0);
  }
#pragma unroll
  for (int i = 0; i < 2; i++)
#pragma unroll
    for (int dj = 0; dj < 4; dj++)
#pragma unroll
      for (int r = 0; r < 4; r++) {
        int n = n0 + w * 32 + i * 16 + (l >> 4) * 4 + r;
        int d = dj * 16 + lr;
        size_t idx = ((size_t)b * 4096 + n) * 1024 + h * 64 + d;
        attn[idx] = f2bf(oa[i][dj][r]);
      }
}

// =======================================================================
extern "C" void kernel_launch(void* const* d_in, const int* in_sizes, int n_in,
                              void* d_out, int out_size, void* d_ws, size_t ws_size,
                              hipStream_t stream) {
  const float* x  = (const float*)d_in[0];
  const float* Wq = (const float*)d_in[1];
  const float* Wk = (const float*)d_in[2];
  const float* Wv = (const float*)d_in[3];
  const float* Wo = (const float*)d_in[4];
  const float* Wc = (const float*)d_in[5];
  float* out = (float*)d_out;

  char* p = (char*)d_ws;
  auto alloc = [&](size_t bytes) { char* r = p; p += (bytes + 255) & ~(size_t)255; return r; };
  const size_t TOK = 16384ull * 1024;
  u16*  xb   = (u16*)alloc(TOK * 2);          // x bf16; later reused as attn buffer
  u16*  qb   = (u16*)alloc(TOK * 2);
  u16*  kb   = (u16*)alloc(TOK * 2);
  u16*  vt   = (u16*)alloc(64ull * 64 * VT_STRIDE * 2);
  u16*  wall = (u16*)alloc(4096ull * 1024 * 2);   // [Wq;Wk;Wv;Wo] stacked bf16
  float* xlp = (float*)alloc(2ull * 256 * 1024 * 4);   // two 32-row partial sums
  float* ql  = (float*)alloc(64ull * 4096 * 4);
  float* kl  = (float*)alloc(64ull * 4096 * 4);
  u16*  qlb  = (u16*)alloc(64ull * 4096 * 2);
  u16*  klb  = (u16*)alloc(64ull * 4096 * 2);
  float* a2b = (float*)alloc(64ull * 4096 * 4);
  float* Zp  = (float*)alloc(16ull * 64 * 4096 * 4);
  float* dp  = (float*)alloc(16ull * 64 * 64 * 4);
  u16*  z2tb = (u16*)alloc(64ull * 4096 * 2);
  float* scl = (float*)alloc(256);
  (void)ws_size; (void)in_sizes; (void)n_in; (void)out_size;

  k_prep<<<4672, 256, 0, stream>>>(x, xb, xlp, scl, Wq, Wk, Wv, Wo, wall, vt);

  // QKV: M=16384, N=3072 -> 64 x 12 tiles = 768 blocks; v lands transposed in vt
  k_gemm256<0><<<768, 512, 0, stream>>>(xb, wall, qb, kb, vt, nullptr, 12);

  k_landproj<<<dim3(4, 32, 2), 256, 0, stream>>>(xlp, Wq, Wk, ql, kl, qlb, klb);
  k_a3a2<<<dim3(64, 17), 256, 0, stream>>>(qlb, kb, vt, Zp, dp, ql, kl, a2b, scl);
  k_pinv<<<64, 256, 0, stream>>>(a2b, Zp, dp, scl, z2tb);

  k_comb<<<dim3(64, 32), 256, 0, stream>>>(qb, klb, z2tb, vt, Wc, xb);
  // out-proj: M=16384, N=1024 -> 64 x 4 tiles = 256 blocks
  k_gemm256<1><<<256, 512, 0, stream>>>(xb, wall + 3ull * 1048576, nullptr, nullptr, nullptr, out, 4);
}